// Round 2
// baseline (476.548 us; speedup 1.0000x reference)
//
#include <hip/hip_runtime.h>

#define NB 128
#define SSEQ 1024
#define TD 512
#define TSTR 516   // ts row stride (halfs): 258 dw == 2 mod 4 -> PV gather quad-alias 2-way (free)

typedef _Float16 half8 __attribute__((ext_vector_type(8)));
typedef _Float16 half4 __attribute__((ext_vector_type(4)));
typedef float f32x4 __attribute__((ext_vector_type(4)));

// ---------------- shared NT GEMM body, fp16 MFMA, fp32 accum, fused dtype convert ----------------
// C[m][n] = sum_k A[m][k]*B[n][k]; 64x64 tile, 4 waves.
// AM: 0 = A fp16, 1 = A fp32 (convert in staging), 2 = A fp32 scaled by 1/aRowScale[row*8+sp]
// BM: 0 = B fp16, 1 = B fp32
// outMode: 0 = fp32 store, 1 = fp16 store, 2 = fp32 store to outF + sp*oSplit (split-K partials)
//          3 = fp32 atomicAdd into outF (split-K accumulate; bias applied by sp==0 only)
template<int AM, int BM>
__device__ __forceinline__ void gemm_body(
    const void* __restrict__ Av, int lda, long aSZ,
    const void* __restrict__ Bv, int ldb, long bSZ,
    const float* __restrict__ bias, const float* __restrict__ aRowScale,
    float scale, int doRelu, int outMode,
    float* __restrict__ outF, _Float16* __restrict__ outH,
    int ldc, int cColOff, int kTiles, long oSplit,
    int mt, int nt, int sp, int bz, int tid)
{
  __shared__ _Float16 As[64][72];
  __shared__ _Float16 Bs[64][72];
  int r = tid >> 2, kq = (tid & 3) * 16;
  int w = tid >> 6, l = tid & 63;
  long aoff = (long)bz * aSZ + (long)(mt * 64 + r) * lda + (long)sp * kTiles * 64 + kq;
  long boff = (long)bz * bSZ + (long)(nt * 64 + r) * ldb + (long)sp * kTiles * 64 + kq;
  const _Float16* apH = (const _Float16*)Av + aoff;
  const float*    apF = (const float*)Av + aoff;
  const _Float16* bpH = (const _Float16*)Bv + boff;
  const float*    bpF = (const float*)Bv + boff;
  float srA = 1.0f;
  if constexpr (AM == 2) srA = 1.0f / aRowScale[(mt * 64 + r) * 8 + sp];

  half8 pa0, pa1, pb0, pb1;
  f32x4 qa0, qa1, qa2, qa3, qc0, qc1, qc2, qc3;
  if constexpr (AM == 0) { pa0 = *(const half8*)apH; pa1 = *(const half8*)(apH + 8); }
  else { qa0 = *(const f32x4*)apF; qa1 = *(const f32x4*)(apF + 4);
         qa2 = *(const f32x4*)(apF + 8); qa3 = *(const f32x4*)(apF + 12); }
  if constexpr (BM == 0) { pb0 = *(const half8*)bpH; pb1 = *(const half8*)(bpH + 8); }
  else { qc0 = *(const f32x4*)bpF; qc1 = *(const f32x4*)(bpF + 4);
         qc2 = *(const f32x4*)(bpF + 8); qc3 = *(const f32x4*)(bpF + 12); }

  f32x4 acc[4];
  #pragma unroll
  for (int c = 0; c < 4; ++c) acc[c] = (f32x4){0.f, 0.f, 0.f, 0.f};
  int fr = l & 15, fo = (l >> 4) * 8;
  for (int kt = 0; kt < kTiles; ++kt) {
    __syncthreads();
    if constexpr (AM == 0) {
      *(half8*)&As[r][kq] = pa0; *(half8*)&As[r][kq + 8] = pa1;
    } else {
      f32x4 s0 = qa0, s1 = qa1, s2 = qa2, s3 = qa3;
      if constexpr (AM == 2) { s0 *= srA; s1 *= srA; s2 *= srA; s3 *= srA; }
      *(half4*)&As[r][kq + 0]  = __builtin_convertvector(s0, half4);
      *(half4*)&As[r][kq + 4]  = __builtin_convertvector(s1, half4);
      *(half4*)&As[r][kq + 8]  = __builtin_convertvector(s2, half4);
      *(half4*)&As[r][kq + 12] = __builtin_convertvector(s3, half4);
    }
    if constexpr (BM == 0) {
      *(half8*)&Bs[r][kq] = pb0; *(half8*)&Bs[r][kq + 8] = pb1;
    } else {
      *(half4*)&Bs[r][kq + 0]  = __builtin_convertvector(qc0, half4);
      *(half4*)&Bs[r][kq + 4]  = __builtin_convertvector(qc1, half4);
      *(half4*)&Bs[r][kq + 8]  = __builtin_convertvector(qc2, half4);
      *(half4*)&Bs[r][kq + 12] = __builtin_convertvector(qc3, half4);
    }
    __syncthreads();
    if (kt + 1 < kTiles) {
      apH += 64; apF += 64; bpH += 64; bpF += 64;
      if constexpr (AM == 0) { pa0 = *(const half8*)apH; pa1 = *(const half8*)(apH + 8); }
      else { qa0 = *(const f32x4*)apF; qa1 = *(const f32x4*)(apF + 4);
             qa2 = *(const f32x4*)(apF + 8); qa3 = *(const f32x4*)(apF + 12); }
      if constexpr (BM == 0) { pb0 = *(const half8*)bpH; pb1 = *(const half8*)(bpH + 8); }
      else { qc0 = *(const f32x4*)bpF; qc1 = *(const f32x4*)(bpF + 4);
             qc2 = *(const f32x4*)(bpF + 8); qc3 = *(const f32x4*)(bpF + 12); }
    }
    #pragma unroll
    for (int ks = 0; ks < 2; ++ks) {
      half8 af = *(const half8*)&As[16 * w + fr][ks * 32 + fo];
      #pragma unroll
      for (int c = 0; c < 4; ++c) {
        half8 bf = *(const half8*)&Bs[16 * c + fr][ks * 32 + fo];
        acc[c] = __builtin_amdgcn_mfma_f32_16x16x32_f16(af, bf, acc[c], 0, 0, 0);
      }
    }
  }
  int lrow = (l >> 4) * 4, lcol = l & 15;
  #pragma unroll
  for (int c = 0; c < 4; ++c) {
    #pragma unroll
    for (int rr = 0; rr < 4; ++rr) {
      int gm = mt * 64 + 16 * w + lrow + rr;
      int gn = nt * 64 + 16 * c + lcol;
      int ecol = gn + bz * cColOff;
      float vv = acc[c][rr];
      if (bias && sp == 0) vv += bias[ecol];
      vv *= scale;
      if (doRelu) vv = fmaxf(vv, 0.f);
      long oidx = (long)gm * ldc + ecol;
      if (outMode == 0) outF[oidx] = vv;
      else if (outMode == 1) outH[oidx] = (_Float16)vv;
      else if (outMode == 2) outF[oidx + (long)sp * oSplit] = vv;
      else atomicAdd(&outF[oidx], vv);
    }
  }
}

template<int AM, int BM>
__global__ __launch_bounds__(256) void k_gemm(
    const void* __restrict__ Av, int lda, long aSZ,
    const void* __restrict__ Bv, int ldb, long bSZ,
    const float* __restrict__ bias, const float* __restrict__ aRowScale,
    float scale, int doRelu, int outMode,
    float* __restrict__ outF, _Float16* __restrict__ outH,
    int ldc, int cColOff, int mtiles, int kTiles, long oSplit)
{
  gemm_body<AM, BM>(Av, lda, aSZ, Bv, ldb, bSZ, bias, aRowScale, scale, doRelu,
                    outMode, outF, outH, ldc, cColOff, kTiles, oSplit,
                    (int)blockIdx.x % mtiles, (int)blockIdx.x / mtiles,
                    (int)blockIdx.y, (int)blockIdx.z, (int)threadIdx.x);
}

// ---------------- prep (blocks 0-511: G + chores; 512-1023: M + obo8) + fc1 GEMM (1024-1215) ----
// G16T[h][g][f] = 0.125*sum_d Wq[64h+d,f]Wk[64h+d,g] (fp16, NT-ready); cvec/gb/qbc bias terms;
// M16T[e][h*512+g] = sum_d Wv[64h+d,g]Wo[e,64h+d]; obo8[h][e] = sum_d Wo[e,64h+d]bv[64h+d];
// zeroes pu/pl and qk16 heads 8-15.
__global__ __launch_bounds__(256) void k_prepfc1(
    const float* __restrict__ Wq, const float* __restrict__ Wk,
    const float* __restrict__ bq, const float* __restrict__ bk,
    _Float16* __restrict__ G16T, float* __restrict__ gb,
    float* __restrict__ qbc, float* __restrict__ cvec,
    float* __restrict__ pz, _Float16* __restrict__ qz,
    const float* __restrict__ v, const float* __restrict__ W1,
    const float* __restrict__ b1, _Float16* __restrict__ x16,
    const float* __restrict__ Wv, const float* __restrict__ Wo,
    const float* __restrict__ bv, _Float16* __restrict__ M16,
    float* __restrict__ obo8)
{
  int bx = blockIdx.x, tid = threadIdx.x;
  if (bx >= 1024) {
    int s = bx - 1024;   // 192 blocks: mtiles=24, ntiles=8
    gemm_body<1, 1>(v, 768, 0, W1, 768, 0, b1, nullptr, 1.f, 1, 1,
                    nullptr, x16, 512, 0, 12, 0, s % 24, s / 24, 0, 0, tid);
    return;
  }
  __shared__ float SA[64][68];
  __shared__ float SB[64][68];
  __shared__ float sv0[64], sv1[64];
  int r = tid >> 2, cq = (tid & 3) * 16;
  int te = tid & 15, td = tid >> 4;

  if (bx >= 512) {
    // ---- M-prep: M16T[e][h*512+g] = sum_d Wv[64h+d,g] * Wo[e,64h+d] ----
    int b2 = bx - 512;
    int h = b2 >> 6, et = (b2 >> 3) & 7, gt = b2 & 7;
    const float* wvp = Wv + (long)(h * 64 + r) * 512 + gt * 64 + cq;
    const float* wop = Wo + (long)(et * 64 + r) * 512 + h * 64 + cq;
    #pragma unroll
    for (int c = 0; c < 4; ++c)
      *(f32x4*)&SA[r][cq + 4 * c] = *(const f32x4*)(wvp + 4 * c);   // SA[d][g]
    #pragma unroll
    for (int c = 0; c < 4; ++c) {
      f32x4 x = *(const f32x4*)(wop + 4 * c);                       // coalesced Wo rows
      #pragma unroll
      for (int i = 0; i < 4; ++i) SB[cq + 4 * c + i][r] = x[i];     // SB[d][e] (transposed store)
    }
    if (tid < 64) sv0[tid] = bv[h * 64 + tid];
    __syncthreads();
    float acc[4][4];
    #pragma unroll
    for (int a = 0; a < 4; ++a)
      #pragma unroll
      for (int d = 0; d < 4; ++d) acc[a][d] = 0.f;
    #pragma unroll 4
    for (int jj = 0; jj < 64; ++jj) {
      f32x4 av = *(const f32x4*)&SA[jj][te * 4];
      f32x4 bt = *(const f32x4*)&SB[jj][td * 4];
      #pragma unroll
      for (int a = 0; a < 4; ++a)
        #pragma unroll
        for (int d = 0; d < 4; ++d) acc[a][d] = fmaf(av[a], bt[d], acc[a][d]);
    }
    #pragma unroll
    for (int d = 0; d < 4; ++d) {
      half4 hv = { (_Float16)acc[0][d], (_Float16)acc[1][d],
                   (_Float16)acc[2][d], (_Float16)acc[3][d] };
      *(half4*)(M16 + (long)(et * 64 + td * 4 + d) * 4096 + h * 512 + gt * 64 + te * 4) = hv;
    }
    if (gt == 0 && te == 0) {
      float s0 = 0.f, s1 = 0.f, s2 = 0.f, s3 = 0.f;
      for (int jj = 0; jj < 64; ++jj) {
        f32x4 bt = *(const f32x4*)&SB[jj][td * 4];
        float bb = sv0[jj];
        s0 = fmaf(bt[0], bb, s0); s1 = fmaf(bt[1], bb, s1);
        s2 = fmaf(bt[2], bb, s2); s3 = fmaf(bt[3], bb, s3);
      }
      obo8[h * 512 + et * 64 + td * 4 + 0] = s0;
      obo8[h * 512 + et * 64 + td * 4 + 1] = s1;
      obo8[h * 512 + et * 64 + td * 4 + 2] = s2;
      obo8[h * 512 + et * 64 + td * 4 + 3] = s3;
    }
    return;
  }

  // ---- G-prep + zero chores ----
  int b = bx;
  int gid = b * 256 + tid;
  for (long i = gid; i < 131328; i += 131072)
    *(f32x4*)(pz + 4 * i) = (f32x4){0.f, 0.f, 0.f, 0.f};
  {
    long i4 = (long)gid * 4;
    long n = i4 >> 12, off = i4 & 4095;
    *(half4*)(qz + n * 8192 + 4096 + off) = (half4){(_Float16)0, (_Float16)0, (_Float16)0, (_Float16)0};
  }
  int h = b >> 6, et = (b >> 3) & 7, dt = b & 7;
  const float* wqp = Wq + (long)(h * 64 + r) * 512 + et * 64 + cq;
  const float* wkp = Wk + (long)(h * 64 + r) * 512 + dt * 64 + cq;
  #pragma unroll
  for (int c = 0; c < 4; ++c) {
    *(f32x4*)&SA[r][cq + 4 * c] = *(const f32x4*)(wqp + 4 * c);
    *(f32x4*)&SB[r][cq + 4 * c] = *(const f32x4*)(wkp + 4 * c);
  }
  if (tid < 64) { sv0[tid] = bq[h * 64 + tid]; sv1[tid] = bk[h * 64 + tid]; }
  __syncthreads();
  float acc[4][4];
  #pragma unroll
  for (int a = 0; a < 4; ++a)
    #pragma unroll
    for (int d = 0; d < 4; ++d) acc[a][d] = 0.f;
  #pragma unroll 4
  for (int j = 0; j < 64; ++j) {
    f32x4 av = *(const f32x4*)&SA[j][te * 4];
    f32x4 bv4 = *(const f32x4*)&SB[j][td * 4];
    #pragma unroll
    for (int a = 0; a < 4; ++a)
      #pragma unroll
      for (int d = 0; d < 4; ++d) acc[a][d] = fmaf(av[a], bv4[d], acc[a][d]);
  }
  #pragma unroll
  for (int d = 0; d < 4; ++d) {
    half4 hv = { (_Float16)(0.125f * acc[0][d]), (_Float16)(0.125f * acc[1][d]),
                 (_Float16)(0.125f * acc[2][d]), (_Float16)(0.125f * acc[3][d]) };
    *(half4*)(G16T + (long)h * 262144 + (long)(dt * 64 + td * 4 + d) * 512 + et * 64 + te * 4) = hv;
  }
  if (dt == 0 && td == 0) {
    #pragma unroll
    for (int i = 0; i < 4; ++i) {
      float s = 0.f;
      for (int j = 0; j < 64; ++j) s = fmaf(SA[j][te * 4 + i], sv1[j], s);
      gb[h * 512 + et * 64 + te * 4 + i] = 0.125f * s;
    }
  }
  if (et == 0 && te == 0) {
    #pragma unroll
    for (int i = 0; i < 4; ++i) {
      float s = 0.f;
      for (int j = 0; j < 64; ++j) s = fmaf(SB[j][td * 4 + i], sv0[j], s);
      cvec[h * 512 + dt * 64 + td * 4 + i] = 0.125f * s;
    }
  }
  if (et == 0 && dt == 0 && tid == 0) {
    float s = 0.f;
    for (int j = 0; j < 64; ++j) s = fmaf(sv0[j], sv1[j], s);
    qbc[h] = 0.125f * s;
  }
}

// ---------------- vfeat = relu(sum_splits + b2): output 0 + fp16 copy; obo = bo + sum_h obo8 ----
__global__ __launch_bounds__(256) void k_vfeat(
    const float* __restrict__ vacc, const float* __restrict__ b2,
    float* __restrict__ outF, _Float16* __restrict__ vf16,
    const float* __restrict__ obo8, const float* __restrict__ bo,
    float* __restrict__ obo)
{
  int i = blockIdx.x * 256 + threadIdx.x;
  float vv = b2[i & 511];
  #pragma unroll
  for (int sp = 0; sp < 16; ++sp) vv += vacc[sp * 65536 + i];
  vv = fmaxf(vv, 0.f);
  outF[i] = vv;
  vf16[i] = (_Float16)vv;
  if (i < 512) {
    float s = bo[i];
    #pragma unroll
    for (int h = 0; h < 8; ++h) s += obo8[h * 512 + i];
    obo[i] = s;
  }
}

// ---------------- qk16 GEMM (blocks 0-127) + qb dot / out-zero (blocks 128-255) ----------------
__global__ __launch_bounds__(256) void k_qkqb(
    const _Float16* __restrict__ vf16, const _Float16* __restrict__ G16T,
    const float* __restrict__ cvec, const float* __restrict__ gb,
    const float* __restrict__ qbc, _Float16* __restrict__ qk16,
    float* __restrict__ qb, float* __restrict__ outz)
{
  int bx = blockIdx.x, tid = threadIdx.x;
  if (bx < 128) {
    int z = bx >> 4, s = bx & 15;   // mtiles=2, ntiles=8, 8 heads
    gemm_body<0, 0>(vf16, 512, 0, G16T, 512, 262144, cvec, nullptr, 1.f, 0, 1,
                    nullptr, qk16, 8192, 512, 8, 0, s % 2, s / 2, 0, z, tid);
    return;
  }
  int n = bx - 128;
  float* oz = outz + (long)n * 512;    // zero attn-out slab for atomic split-K epilogue
  oz[tid] = 0.f; oz[tid + 256] = 0.f;
  __shared__ float qs[512];
  qs[tid] = (float)vf16[n * 512 + tid];
  qs[tid + 256] = (float)vf16[n * 512 + tid + 256];
  __syncthreads();
  int h = tid >> 5, j = tid & 31;
  float p = 0.f;
  for (int e = j; e < 512; e += 32) p = fmaf(qs[e], gb[h * 512 + e], p);
  #pragma unroll
  for (int m = 1; m < 32; m <<= 1) p += __shfl_xor(p, m, 32);
  if (j == 0) qb[n * 8 + h] = p + qbc[h];
}

// ---------------- fused streaming attention: one-shot 64-row tile, all-wave MFMA ----------------
// Wave-local staging: wave w loads/converts its own rows 16w..16w+15 -> no stage barrier.
// Scores: wave w computes its rows (16 MFMA, K=512); weights -> wst[16][72] fp16; pl via atomics.
// PV: O[h][d] += W[h][s]*T[s][d], 16 MFMA per wave over K=64. ONE barrier total.
__global__ __launch_bounds__(256) void k_attn(
    const float* __restrict__ t, const int* __restrict__ tlen,
    const _Float16* __restrict__ qk16, const float* __restrict__ qb,
    float* __restrict__ pu, float* __restrict__ pl)
{
  int n = blockIdx.x >> 4, j = blockIdx.x & 15;
  int len = tlen[n];
  int base = j * 64;
  if (base >= len) return;
  int s1 = base + 64; if (s1 > len) s1 = len;
  int tid = threadIdx.x, wid = tid >> 6, l = tid & 63;
  int fr = l & 15, fo = (l >> 4) * 8;

  __shared__ __align__(16) _Float16 ts[64][TSTR];   // 64.5 KB
  __shared__ __align__(16) _Float16 wst[16][72];    // stride 36 dw: A-read conflict-free

  const float* tn = t + (long)n * SSEQ * TD;
  // ---- wave-local stage: rows 16*wid .. 16*wid+15, fp32->fp16, 2-row pipeline ----
  {
    f32x4 a0, a1, b0, b1;
    auto ld = [&](int rr, f32x4& x0, f32x4& x1) {
      int sg = base + 16 * wid + rr;
      if (sg < s1) {
        const float* p = tn + (long)sg * TD;
        x0 = *(const f32x4*)(p + 4 * l);
        x1 = *(const f32x4*)(p + 256 + 4 * l);
      } else {
        x0 = (f32x4){0.f,0.f,0.f,0.f}; x1 = (f32x4){0.f,0.f,0.f,0.f};
      }
    };
    ld(0, a0, a1); ld(1, b0, b1);
    #pragma unroll
    for (int rr = 0; rr < 16; rr += 2) {
      half4 h0 = __builtin_convertvector(a0, half4);
      half4 h1 = __builtin_convertvector(a1, half4);
      int row = 16 * wid + rr;
      if (rr + 2 < 16) ld(rr + 2, a0, a1);
      *(half4*)&ts[row][4 * l] = h0;
      *(half4*)&ts[row][256 + 4 * l] = h1;
      half4 g0 = __builtin_convertvector(b0, half4);
      half4 g1 = __builtin_convertvector(b1, half4);
      if (rr + 3 < 16) ld(rr + 3, b0, b1);
      *(half4*)&ts[row + 1][4 * l] = g0;
      *(half4*)&ts[row + 1][256 + 4 * l] = g1;
    }
  }
  // ---- scores on own rows (wave-internal LDS dependency; no block barrier) ----
  {
    const _Float16* qn = qk16 + (long)n * 8192 + fr * 512 + fo;
    float qbr = (fr < 8) ? qb[n * 8 + fr] : 0.f;
    f32x4 acc = (f32x4){0.f, 0.f, 0.f, 0.f};
    __builtin_amdgcn_s_setprio(1);
    #pragma unroll 4
    for (int kt = 0; kt < 16; ++kt) {
      half8 bf = *(const half8*)(qn + kt * 32);
      const _Float16* ap = &ts[16 * wid + fr][kt * 32 + fo];
      half4 alo = *(const half4*)ap;             // b64 pair (row stride 8-aligned)
      half4 ahi = *(const half4*)(ap + 4);
      half8 af = { alo[0], alo[1], alo[2], alo[3], ahi[0], ahi[1], ahi[2], ahi[3] };
      acc = __builtin_amdgcn_mfma_f32_16x16x32_f16(af, bf, acc, 0, 0, 0);
    }
    __builtin_amdgcn_s_setprio(0);
    float lac = 0.f;
    #pragma unroll
    for (int r = 0; r < 4; ++r) {
      int sl = 16 * wid + (l >> 4) * 4 + r;
      float wv = (fr < 8 && base + sl < s1) ? __expf(acc[r] + qbr) : 0.f;
      wst[fr][sl] = (_Float16)wv;
      lac += wv;
    }
    if (fr < 8) atomicAdd(&pl[n * 8 + fr], lac);
  }
  __syncthreads();
  // ---- PV via MFMA: wave owns d-range [128*wid, +128); 8 col-tiles x K=64 ----
  f32x4 upv[8];
  #pragma unroll
  for (int dt = 0; dt < 8; ++dt) upv[dt] = (f32x4){0.f, 0.f, 0.f, 0.f};
  __builtin_amdgcn_s_setprio(1);
  #pragma unroll
  for (int dt = 0; dt < 8; ++dt) {
    int dcol = 128 * wid + dt * 16 + fr;
    #pragma unroll
    for (int ks = 0; ks < 2; ++ks) {
      half8 af = *(const half8*)&wst[fr][ks * 32 + fo];
      half8 bf;
      #pragma unroll
      for (int jj = 0; jj < 8; ++jj) bf[jj] = ts[ks * 32 + fo + jj][dcol];
      upv[dt] = __builtin_amdgcn_mfma_f32_16x16x32_f16(af, bf, upv[dt], 0, 0, 0);
    }
  }
  __builtin_amdgcn_s_setprio(0);
  // ---- epilogue: lane quad q holds heads 4q..4q+3 (valid q<2) ----
  int quad = l >> 4;
  float* pn = pu + (long)n * 4096;
  if (quad < 2) {
    #pragma unroll
    for (int dt = 0; dt < 8; ++dt) {
      int d = 128 * wid + dt * 16 + fr;
      #pragma unroll
      for (int r = 0; r < 4; ++r)
        atomicAdd(&pn[(quad * 4 + r) * 512 + d], upv[dt][r]);
    }
  }
}

extern "C" void kernel_launch(void* const* d_in, const int* in_sizes, int n_in,
                              void* d_out, int out_size, void* d_ws, size_t ws_size,
                              hipStream_t stream)
{
  const float* v    = (const float*)d_in[0];
  const float* t    = (const float*)d_in[1];
  const int*   tlen = (const int*)d_in[2];
  const float* W1   = (const float*)d_in[3];
  const float* b1   = (const float*)d_in[4];
  const float* W2   = (const float*)d_in[5];
  const float* b2   = (const float*)d_in[6];
  const float* Wq   = (const float*)d_in[7];
  const float* Wk   = (const float*)d_in[8];
  const float* Wv   = (const float*)d_in[9];
  const float* bq   = (const float*)d_in[10];
  const float* bk   = (const float*)d_in[11];
  const float* bv   = (const float*)d_in[12];
  const float* Wo   = (const float*)d_in[13];
  const float* bo   = (const float*)d_in[14];
  float* out = (float*)d_out;

  // ---- workspace layout: fp16 region then fp32 region (total ~17.7 MB << ws) ----
  _Float16* hb   = (_Float16*)d_ws;
  _Float16* x16  = hb;                  // 786432   [1536][512]
  _Float16* vf16 = hb + 786432l;        // 65536    [128][512]
  _Float16* qk16 = hb + 851968l;        // 1048576  [128][16][512]
  _Float16* G16T = hb + 1900544l;       // 2097152  [8][512 g][512 f]
  _Float16* M16  = hb + 3997696l;       // 2097152  [512 e][8*512 (h,g)]
  float* fb   = (float*)(hb + 6094848l);
  float* vacc = fb;                     // 16*65536 = 1048576
  float* pu   = fb + 1048576l;          // 524288   [128][8][512]
  float* pl   = fb + 1572864l;          // 1024     [128][8]  (zeroed with pu)
  float* qb   = fb + 1573888l;          // 1024
  float* gb   = fb + 1574912l;          // 4096     [8][512]
  float* qbc  = fb + 1579008l;          // 16
  float* cvec = fb + 1579024l;          // 4096     [8][512]
  float* obo8 = fb + 1583120l;          // 4096     [8][512]
  float* obo  = fb + 1587216l;          // 512      bo + Wo.bv

  // prep (G/gb/cvec/qbc + M/obo8 + zero pu/pl/qk16-pad) || fc1 GEMM
  k_prepfc1<<<1216, 256, 0, stream>>>(Wq, Wk, bq, bk, G16T, gb, qbc, cvec,
                                      pu, qk16, v, W1, b1, x16, Wv, Wo, bv, M16, obo8);
  // fc2 split-K(16): A=x16 fp16 [128x6144], B=W2 fp32 -> partials vacc[16][65536]
  k_gemm<0,1><<<dim3(16, 16, 1), 256, 0, stream>>>(x16, 6144, 0, W2, 6144, 0,
      nullptr, nullptr, 1.f, 0, 2, vacc, nullptr, 512, 0, 2, 6, 65536);
  k_vfeat<<<256, 256, 0, stream>>>(vacc, b2, out, vf16, obo8, bo, obo);
  // qk16 = vf16 @ G16T (+cvec) batched over heads  ||  qb = vf16.gb + qbc  ||  zero out[65536..]
  k_qkqb<<<256, 256, 0, stream>>>(vf16, G16T, cvec, gb, qbc, qk16, qb, out + 65536);
  k_attn<<<NB * 16, 256, 0, stream>>>(t, tlen, qk16, qb, pu, pl);
  // attn_out = (pu/pl) @ M16 + obo, split-K over heads with atomic epilogue -> output 1
  k_gemm<2,0><<<dim3(16, 8, 1), 256, 0, stream>>>(pu, 4096, 0, M16, 4096, 0,
      obo, pl, 1.f, 0, 3, out + 65536, nullptr, 512, 0, 2, 8, 0);
}

// Round 3
// 455.460 us; speedup vs baseline: 1.0463x; 1.0463x over previous
//
#include <hip/hip_runtime.h>

#define NB 128
#define SSEQ 1024
#define TD 512
#define TSTR 516   // ts row stride (halfs): 258 dw == 2 mod 4 -> PV gather quad-alias 2-way (free)

typedef _Float16 half8 __attribute__((ext_vector_type(8)));
typedef _Float16 half4 __attribute__((ext_vector_type(4)));
typedef float f32x4 __attribute__((ext_vector_type(4)));

// ---------------- shared NT GEMM body, fp16 MFMA, fp32 accum, fused dtype convert ----------------
// C[m][n] = sum_k A[m][k]*B[n][k]; 64x64 tile, 4 waves.
// AM: 0 = A fp16, 1 = A fp32 (convert in staging), 2 = A fp32 scaled by 1/aRowScale[row*8+sp]
// BM: 0 = B fp16, 1 = B fp32
// outMode: 0 = fp32 store, 1 = fp16 store, 2 = fp32 store to outF + sp*oSplit (split-K partials)
//          3 = fp32 atomicAdd into outF (split-K accumulate; bias at sp==0, biasS[sp] per split)
template<int AM, int BM>
__device__ __forceinline__ void gemm_body(
    const void* __restrict__ Av, int lda, long aSZ,
    const void* __restrict__ Bv, int ldb, long bSZ,
    const float* __restrict__ bias, const float* __restrict__ biasS,
    const float* __restrict__ aRowScale,
    float scale, int doRelu, int outMode,
    float* __restrict__ outF, _Float16* __restrict__ outH,
    int ldc, int cColOff, int kTiles, long oSplit,
    int mt, int nt, int sp, int bz, int tid)
{
  __shared__ _Float16 As[64][72];
  __shared__ _Float16 Bs[64][72];
  int r = tid >> 2, kq = (tid & 3) * 16;
  int w = tid >> 6, l = tid & 63;
  long aoff = (long)bz * aSZ + (long)(mt * 64 + r) * lda + (long)sp * kTiles * 64 + kq;
  long boff = (long)bz * bSZ + (long)(nt * 64 + r) * ldb + (long)sp * kTiles * 64 + kq;
  const _Float16* apH = (const _Float16*)Av + aoff;
  const float*    apF = (const float*)Av + aoff;
  const _Float16* bpH = (const _Float16*)Bv + boff;
  const float*    bpF = (const float*)Bv + boff;
  float srA = 1.0f;
  if constexpr (AM == 2) srA = 1.0f / aRowScale[(mt * 64 + r) * 8 + sp];

  half8 pa0, pa1, pb0, pb1;
  f32x4 qa0, qa1, qa2, qa3, qc0, qc1, qc2, qc3;
  if constexpr (AM == 0) { pa0 = *(const half8*)apH; pa1 = *(const half8*)(apH + 8); }
  else { qa0 = *(const f32x4*)apF; qa1 = *(const f32x4*)(apF + 4);
         qa2 = *(const f32x4*)(apF + 8); qa3 = *(const f32x4*)(apF + 12); }
  if constexpr (BM == 0) { pb0 = *(const half8*)bpH; pb1 = *(const half8*)(bpH + 8); }
  else { qc0 = *(const f32x4*)bpF; qc1 = *(const f32x4*)(bpF + 4);
         qc2 = *(const f32x4*)(bpF + 8); qc3 = *(const f32x4*)(bpF + 12); }

  f32x4 acc[4];
  #pragma unroll
  for (int c = 0; c < 4; ++c) acc[c] = (f32x4){0.f, 0.f, 0.f, 0.f};
  int fr = l & 15, fo = (l >> 4) * 8;
  for (int kt = 0; kt < kTiles; ++kt) {
    __syncthreads();
    if constexpr (AM == 0) {
      *(half8*)&As[r][kq] = pa0; *(half8*)&As[r][kq + 8] = pa1;
    } else {
      f32x4 s0 = qa0, s1 = qa1, s2 = qa2, s3 = qa3;
      if constexpr (AM == 2) { s0 *= srA; s1 *= srA; s2 *= srA; s3 *= srA; }
      *(half4*)&As[r][kq + 0]  = __builtin_convertvector(s0, half4);
      *(half4*)&As[r][kq + 4]  = __builtin_convertvector(s1, half4);
      *(half4*)&As[r][kq + 8]  = __builtin_convertvector(s2, half4);
      *(half4*)&As[r][kq + 12] = __builtin_convertvector(s3, half4);
    }
    if constexpr (BM == 0) {
      *(half8*)&Bs[r][kq] = pb0; *(half8*)&Bs[r][kq + 8] = pb1;
    } else {
      *(half4*)&Bs[r][kq + 0]  = __builtin_convertvector(qc0, half4);
      *(half4*)&Bs[r][kq + 4]  = __builtin_convertvector(qc1, half4);
      *(half4*)&Bs[r][kq + 8]  = __builtin_convertvector(qc2, half4);
      *(half4*)&Bs[r][kq + 12] = __builtin_convertvector(qc3, half4);
    }
    __syncthreads();
    if (kt + 1 < kTiles) {
      apH += 64; apF += 64; bpH += 64; bpF += 64;
      if constexpr (AM == 0) { pa0 = *(const half8*)apH; pa1 = *(const half8*)(apH + 8); }
      else { qa0 = *(const f32x4*)apF; qa1 = *(const f32x4*)(apF + 4);
             qa2 = *(const f32x4*)(apF + 8); qa3 = *(const f32x4*)(apF + 12); }
      if constexpr (BM == 0) { pb0 = *(const half8*)bpH; pb1 = *(const half8*)(bpH + 8); }
      else { qc0 = *(const f32x4*)bpF; qc1 = *(const f32x4*)(bpF + 4);
             qc2 = *(const f32x4*)(bpF + 8); qc3 = *(const f32x4*)(bpF + 12); }
    }
    #pragma unroll
    for (int ks = 0; ks < 2; ++ks) {
      half8 af = *(const half8*)&As[16 * w + fr][ks * 32 + fo];
      #pragma unroll
      for (int c = 0; c < 4; ++c) {
        half8 bf = *(const half8*)&Bs[16 * c + fr][ks * 32 + fo];
        acc[c] = __builtin_amdgcn_mfma_f32_16x16x32_f16(af, bf, acc[c], 0, 0, 0);
      }
    }
  }
  int lrow = (l >> 4) * 4, lcol = l & 15;
  #pragma unroll
  for (int c = 0; c < 4; ++c) {
    #pragma unroll
    for (int rr = 0; rr < 4; ++rr) {
      int gm = mt * 64 + 16 * w + lrow + rr;
      int gn = nt * 64 + 16 * c + lcol;
      int ecol = gn + bz * cColOff;
      float vv = acc[c][rr];
      if (bias && sp == 0) vv += bias[ecol];
      if (biasS) vv += biasS[sp * 512 + ecol];
      vv *= scale;
      if (doRelu) vv = fmaxf(vv, 0.f);
      long oidx = (long)gm * ldc + ecol;
      if (outMode == 0) outF[oidx] = vv;
      else if (outMode == 1) outH[oidx] = (_Float16)vv;
      else if (outMode == 2) outF[oidx + (long)sp * oSplit] = vv;
      else atomicAdd(&outF[oidx], vv);
    }
  }
}

template<int AM, int BM>
__global__ __launch_bounds__(256) void k_gemm(
    const void* __restrict__ Av, int lda, long aSZ,
    const void* __restrict__ Bv, int ldb, long bSZ,
    const float* __restrict__ bias, const float* __restrict__ biasS,
    const float* __restrict__ aRowScale,
    float scale, int doRelu, int outMode,
    float* __restrict__ outF, _Float16* __restrict__ outH,
    int ldc, int cColOff, int mtiles, int kTiles, long oSplit)
{
  gemm_body<AM, BM>(Av, lda, aSZ, Bv, ldb, bSZ, bias, biasS, aRowScale, scale, doRelu,
                    outMode, outF, outH, ldc, cColOff, kTiles, oSplit,
                    (int)blockIdx.x % mtiles, (int)blockIdx.x / mtiles,
                    (int)blockIdx.y, (int)blockIdx.z, (int)threadIdx.x);
}

// ---------------- prep (blocks 0-511: G + zero chores) + fc1 GEMM (blocks 512-703) ----------------
// G16T[h][g][f] = 0.125*sum_d Wq[64h+d,f]Wk[64h+d,g] (fp16, NT-ready); cvec/gb/qbc bias terms;
// zeroes pu/pl and qk16 heads 8-15.
__global__ __launch_bounds__(256) void k_prepfc1(
    const float* __restrict__ Wq, const float* __restrict__ Wk,
    const float* __restrict__ bq, const float* __restrict__ bk,
    _Float16* __restrict__ G16T, float* __restrict__ gb,
    float* __restrict__ qbc, float* __restrict__ cvec,
    float* __restrict__ pz, _Float16* __restrict__ qz,
    const float* __restrict__ v, const float* __restrict__ W1,
    const float* __restrict__ b1, _Float16* __restrict__ x16)
{
  int bx = blockIdx.x, tid = threadIdx.x;
  if (bx >= 512) {
    int s = bx - 512;   // 192 blocks: mtiles=24, ntiles=8
    gemm_body<1, 1>(v, 768, 0, W1, 768, 0, b1, nullptr, nullptr, 1.f, 1, 1,
                    nullptr, x16, 512, 0, 12, 0, s % 24, s / 24, 0, 0, tid);
    return;
  }
  int b = bx;
  int gid = b * 256 + tid;
  for (long i = gid; i < 131328; i += 131072)
    *(f32x4*)(pz + 4 * i) = (f32x4){0.f, 0.f, 0.f, 0.f};
  {
    long i4 = (long)gid * 4;
    long n = i4 >> 12, off = i4 & 4095;
    *(half4*)(qz + n * 8192 + 4096 + off) = (half4){(_Float16)0, (_Float16)0, (_Float16)0, (_Float16)0};
  }
  __shared__ float SA[64][68];
  __shared__ float SB[64][68];
  __shared__ float sv0[64], sv1[64];
  int r = tid >> 2, cq = (tid & 3) * 16;
  int te = tid & 15, td = tid >> 4;
  int h = b >> 6, et = (b >> 3) & 7, dt = b & 7;
  const float* wqp = Wq + (long)(h * 64 + r) * 512 + et * 64 + cq;
  const float* wkp = Wk + (long)(h * 64 + r) * 512 + dt * 64 + cq;
  #pragma unroll
  for (int c = 0; c < 4; ++c) {
    *(f32x4*)&SA[r][cq + 4 * c] = *(const f32x4*)(wqp + 4 * c);
    *(f32x4*)&SB[r][cq + 4 * c] = *(const f32x4*)(wkp + 4 * c);
  }
  if (tid < 64) { sv0[tid] = bq[h * 64 + tid]; sv1[tid] = bk[h * 64 + tid]; }
  __syncthreads();
  float acc[4][4];
  #pragma unroll
  for (int a = 0; a < 4; ++a)
    #pragma unroll
    for (int d = 0; d < 4; ++d) acc[a][d] = 0.f;
  #pragma unroll 4
  for (int j = 0; j < 64; ++j) {
    f32x4 av = *(const f32x4*)&SA[j][te * 4];
    f32x4 bv4 = *(const f32x4*)&SB[j][td * 4];
    #pragma unroll
    for (int a = 0; a < 4; ++a)
      #pragma unroll
      for (int d = 0; d < 4; ++d) acc[a][d] = fmaf(av[a], bv4[d], acc[a][d]);
  }
  #pragma unroll
  for (int d = 0; d < 4; ++d) {
    half4 hv = { (_Float16)(0.125f * acc[0][d]), (_Float16)(0.125f * acc[1][d]),
                 (_Float16)(0.125f * acc[2][d]), (_Float16)(0.125f * acc[3][d]) };
    *(half4*)(G16T + (long)h * 262144 + (long)(dt * 64 + td * 4 + d) * 512 + et * 64 + te * 4) = hv;
  }
  if (dt == 0 && td == 0) {
    #pragma unroll
    for (int i = 0; i < 4; ++i) {
      float s = 0.f;
      for (int j = 0; j < 64; ++j) s = fmaf(SA[j][te * 4 + i], sv1[j], s);
      gb[h * 512 + et * 64 + te * 4 + i] = 0.125f * s;
    }
  }
  if (et == 0 && te == 0) {
    #pragma unroll
    for (int i = 0; i < 4; ++i) {
      float s = 0.f;
      for (int j = 0; j < 64; ++j) s = fmaf(SB[j][td * 4 + i], sv0[j], s);
      cvec[h * 512 + dt * 64 + td * 4 + i] = 0.125f * s;
    }
  }
  if (et == 0 && dt == 0 && tid == 0) {
    float s = 0.f;
    for (int j = 0; j < 64; ++j) s = fmaf(sv0[j], sv1[j], s);
    qbc[h] = 0.125f * s;
  }
}

// ---------------- vfeat (blocks 0-255) + M-prep (blocks 256-767) ----------------
// vfeat = relu(sum_splits + b2) -> output 0 + fp16 copy.
// M16T[e][h*512+g] = sum_d Wv[64h+d,g]Wo[e,64h+d]; obo8[h][e] = sum_d Wo[e,64h+d]bv[64h+d].
// (off the serial critical path: prep stays short; M16/obo8 needed only by the final GEMM)
__global__ __launch_bounds__(256) void k_vfeat(
    const float* __restrict__ vacc, const float* __restrict__ b2,
    float* __restrict__ outF, _Float16* __restrict__ vf16,
    const float* __restrict__ Wv, const float* __restrict__ Wo,
    const float* __restrict__ bv, _Float16* __restrict__ M16,
    float* __restrict__ obo8)
{
  int bx = blockIdx.x, tid = threadIdx.x;
  __shared__ float SA[64][68];
  __shared__ float SB[64][68];
  __shared__ float sv0[64];
  if (bx < 256) {
    int i = bx * 256 + tid;
    float vv = b2[i & 511];
    #pragma unroll
    for (int sp = 0; sp < 16; ++sp) vv += vacc[sp * 65536 + i];
    vv = fmaxf(vv, 0.f);
    outF[i] = vv;
    vf16[i] = (_Float16)vv;
    return;
  }
  int b2i = bx - 256;
  int h = b2i >> 6, et = (b2i >> 3) & 7, gt = b2i & 7;
  int r = tid >> 2, cq = (tid & 3) * 16;
  int te = tid & 15, td = tid >> 4;
  const float* wvp = Wv + (long)(h * 64 + r) * 512 + gt * 64 + cq;
  const float* wop = Wo + (long)(et * 64 + r) * 512 + h * 64 + cq;
  #pragma unroll
  for (int c = 0; c < 4; ++c)
    *(f32x4*)&SA[r][cq + 4 * c] = *(const f32x4*)(wvp + 4 * c);   // SA[d][g]
  #pragma unroll
  for (int c = 0; c < 4; ++c) {
    f32x4 x = *(const f32x4*)(wop + 4 * c);                       // coalesced Wo rows
    #pragma unroll
    for (int i = 0; i < 4; ++i) SB[cq + 4 * c + i][r] = x[i];     // SB[d][e] (transposed store)
  }
  if (tid < 64) sv0[tid] = bv[h * 64 + tid];
  __syncthreads();
  float acc[4][4];
  #pragma unroll
  for (int a = 0; a < 4; ++a)
    #pragma unroll
    for (int d = 0; d < 4; ++d) acc[a][d] = 0.f;
  #pragma unroll 4
  for (int jj = 0; jj < 64; ++jj) {
    f32x4 av = *(const f32x4*)&SA[jj][te * 4];
    f32x4 bt = *(const f32x4*)&SB[jj][td * 4];
    #pragma unroll
    for (int a = 0; a < 4; ++a)
      #pragma unroll
      for (int d = 0; d < 4; ++d) acc[a][d] = fmaf(av[a], bt[d], acc[a][d]);
  }
  #pragma unroll
  for (int d = 0; d < 4; ++d) {
    half4 hv = { (_Float16)acc[0][d], (_Float16)acc[1][d],
                 (_Float16)acc[2][d], (_Float16)acc[3][d] };
    *(half4*)(M16 + (long)(et * 64 + td * 4 + d) * 4096 + h * 512 + gt * 64 + te * 4) = hv;
  }
  if (gt == 0 && te == 0) {
    float s0 = 0.f, s1 = 0.f, s2 = 0.f, s3 = 0.f;
    for (int jj = 0; jj < 64; ++jj) {
      f32x4 bt = *(const f32x4*)&SB[jj][td * 4];
      float bb = sv0[jj];
      s0 = fmaf(bt[0], bb, s0); s1 = fmaf(bt[1], bb, s1);
      s2 = fmaf(bt[2], bb, s2); s3 = fmaf(bt[3], bb, s3);
    }
    obo8[h * 512 + et * 64 + td * 4 + 0] = s0;
    obo8[h * 512 + et * 64 + td * 4 + 1] = s1;
    obo8[h * 512 + et * 64 + td * 4 + 2] = s2;
    obo8[h * 512 + et * 64 + td * 4 + 3] = s3;
  }
}

// ---------------- qk16 GEMM (blocks 0-127) + qb dot / out-zero (blocks 128-255) ----------------
__global__ __launch_bounds__(256) void k_qkqb(
    const _Float16* __restrict__ vf16, const _Float16* __restrict__ G16T,
    const float* __restrict__ cvec, const float* __restrict__ gb,
    const float* __restrict__ qbc, _Float16* __restrict__ qk16,
    float* __restrict__ qb, float* __restrict__ outz)
{
  int bx = blockIdx.x, tid = threadIdx.x;
  if (bx < 128) {
    int z = bx >> 4, s = bx & 15;   // mtiles=2, ntiles=8, 8 heads
    gemm_body<0, 0>(vf16, 512, 0, G16T, 512, 262144, cvec, nullptr, nullptr, 1.f, 0, 1,
                    nullptr, qk16, 8192, 512, 8, 0, s % 2, s / 2, 0, z, tid);
    return;
  }
  int n = bx - 128;
  float* oz = outz + (long)n * 512;    // zero attn-out slab for atomic split-K epilogue
  oz[tid] = 0.f; oz[tid + 256] = 0.f;
  __shared__ float qs[512];
  qs[tid] = (float)vf16[n * 512 + tid];
  qs[tid + 256] = (float)vf16[n * 512 + tid + 256];
  __syncthreads();
  int h = tid >> 5, j = tid & 31;
  float p = 0.f;
  for (int e = j; e < 512; e += 32) p = fmaf(qs[e], gb[h * 512 + e], p);
  #pragma unroll
  for (int m = 1; m < 32; m <<= 1) p += __shfl_xor(p, m, 32);
  if (j == 0) qb[n * 8 + h] = p + qbc[h];
}

// ---------------- fused streaming attention: 4 sequential 64-row tiles per block ----------------
// Block (n,g) owns rows [256g, 256g+256). Wave-local staging (no stage barrier); scores on own
// rows; PV accumulates upv in registers ACROSS tiles; single pu/pl atomic flush at the end
// (4x fewer atomics and qk16 re-reads than one-tile-per-block). 2 barriers per tile.
__global__ __launch_bounds__(256) void k_attn(
    const float* __restrict__ t, const int* __restrict__ tlen,
    const _Float16* __restrict__ qk16, const float* __restrict__ qb,
    float* __restrict__ pu, float* __restrict__ pl)
{
  int n = blockIdx.x >> 2, g = blockIdx.x & 3;
  int len = tlen[n];
  if (g * 256 >= len) return;
  int tid = threadIdx.x, wid = tid >> 6, l = tid & 63;
  int fr = l & 15, fo = (l >> 4) * 8;

  __shared__ __align__(16) _Float16 ts[64][TSTR];   // 64.5 KB
  __shared__ __align__(16) _Float16 wst[16][72];    // stride 36 dw: A-read conflict-free

  const float* tn = t + (long)n * SSEQ * TD;
  const _Float16* qn = qk16 + (long)n * 8192 + fr * 512 + fo;
  float qbr = (fr < 8) ? qb[n * 8 + fr] : 0.f;

  f32x4 upv[8];
  #pragma unroll
  for (int dt = 0; dt < 8; ++dt) upv[dt] = (f32x4){0.f, 0.f, 0.f, 0.f};
  float lsum = 0.f;

  for (int jj = 0; jj < 4; ++jj) {
    int base = g * 256 + jj * 64;
    if (base >= len) break;                       // block-uniform
    int s1 = base + 64; if (s1 > len) s1 = len;
    if (jj) __syncthreads();                      // protect ts/wst from previous PV readers
    // ---- wave-local stage: rows 16*wid .. 16*wid+15, fp32->fp16, 2-row pipeline ----
    {
      f32x4 a0, a1, b0, b1;
      auto ld = [&](int rr, f32x4& x0, f32x4& x1) {
        int sg = base + 16 * wid + rr;
        if (sg < s1) {
          const float* p = tn + (long)sg * TD;
          x0 = *(const f32x4*)(p + 4 * l);
          x1 = *(const f32x4*)(p + 256 + 4 * l);
        } else {
          x0 = (f32x4){0.f,0.f,0.f,0.f}; x1 = (f32x4){0.f,0.f,0.f,0.f};
        }
      };
      ld(0, a0, a1); ld(1, b0, b1);
      #pragma unroll
      for (int rr = 0; rr < 16; rr += 2) {
        half4 h0 = __builtin_convertvector(a0, half4);
        half4 h1 = __builtin_convertvector(a1, half4);
        int row = 16 * wid + rr;
        if (rr + 2 < 16) ld(rr + 2, a0, a1);
        *(half4*)&ts[row][4 * l] = h0;
        *(half4*)&ts[row][256 + 4 * l] = h1;
        half4 g0 = __builtin_convertvector(b0, half4);
        half4 g1 = __builtin_convertvector(b1, half4);
        if (rr + 3 < 16) ld(rr + 3, b0, b1);
        *(half4*)&ts[row + 1][4 * l] = g0;
        *(half4*)&ts[row + 1][256 + 4 * l] = g1;
      }
    }
    // ---- scores on own rows (wave-internal LDS dependency; no block barrier) ----
    {
      f32x4 acc = (f32x4){0.f, 0.f, 0.f, 0.f};
      __builtin_amdgcn_s_setprio(1);
      #pragma unroll 4
      for (int kt = 0; kt < 16; ++kt) {
        half8 bf = *(const half8*)(qn + kt * 32);
        const _Float16* ap = &ts[16 * wid + fr][kt * 32 + fo];
        half4 alo = *(const half4*)ap;             // b64 pair (row stride 8-aligned)
        half4 ahi = *(const half4*)(ap + 4);
        half8 af = { alo[0], alo[1], alo[2], alo[3], ahi[0], ahi[1], ahi[2], ahi[3] };
        acc = __builtin_amdgcn_mfma_f32_16x16x32_f16(af, bf, acc, 0, 0, 0);
      }
      __builtin_amdgcn_s_setprio(0);
      #pragma unroll
      for (int r = 0; r < 4; ++r) {
        int sl = 16 * wid + (l >> 4) * 4 + r;
        float wv = (fr < 8 && base + sl < s1) ? __expf(acc[r] + qbr) : 0.f;
        wst[fr][sl] = (_Float16)wv;
        lsum += wv;
      }
    }
    __syncthreads();
    // ---- PV via MFMA: wave owns d-range [128*wid, +128); 8 col-tiles x K=64; acc across jj ----
    __builtin_amdgcn_s_setprio(1);
    #pragma unroll
    for (int dt = 0; dt < 8; ++dt) {
      int dcol = 128 * wid + dt * 16 + fr;
      #pragma unroll
      for (int ks = 0; ks < 2; ++ks) {
        half8 af = *(const half8*)&wst[fr][ks * 32 + fo];
        half8 bf;
        #pragma unroll
        for (int jx = 0; jx < 8; ++jx) bf[jx] = ts[ks * 32 + fo + jx][dcol];
        upv[dt] = __builtin_amdgcn_mfma_f32_16x16x32_f16(af, bf, upv[dt], 0, 0, 0);
      }
    }
    __builtin_amdgcn_s_setprio(0);
  }
  // ---- single flush: lane quad q holds heads 4q..4q+3 (valid q<2) ----
  int quad = l >> 4;
  float* pn = pu + (long)n * 4096;
  if (quad < 2) {
    #pragma unroll
    for (int dt = 0; dt < 8; ++dt) {
      int d = 128 * wid + dt * 16 + fr;
      #pragma unroll
      for (int r = 0; r < 4; ++r)
        atomicAdd(&pn[(quad * 4 + r) * 512 + d], upv[dt][r]);
    }
  }
  if (fr < 8) atomicAdd(&pl[n * 8 + fr], lsum);
}

extern "C" void kernel_launch(void* const* d_in, const int* in_sizes, int n_in,
                              void* d_out, int out_size, void* d_ws, size_t ws_size,
                              hipStream_t stream)
{
  const float* v    = (const float*)d_in[0];
  const float* t    = (const float*)d_in[1];
  const int*   tlen = (const int*)d_in[2];
  const float* W1   = (const float*)d_in[3];
  const float* b1   = (const float*)d_in[4];
  const float* W2   = (const float*)d_in[5];
  const float* b2   = (const float*)d_in[6];
  const float* Wq   = (const float*)d_in[7];
  const float* Wk   = (const float*)d_in[8];
  const float* Wv   = (const float*)d_in[9];
  const float* bq   = (const float*)d_in[10];
  const float* bk   = (const float*)d_in[11];
  const float* bv   = (const float*)d_in[12];
  const float* Wo   = (const float*)d_in[13];
  const float* bo   = (const float*)d_in[14];
  float* out = (float*)d_out;

  // ---- workspace layout: fp16 region then fp32 region (total ~17.7 MB << ws) ----
  _Float16* hb   = (_Float16*)d_ws;
  _Float16* x16  = hb;                  // 786432   [1536][512]
  _Float16* vf16 = hb + 786432l;        // 65536    [128][512]
  _Float16* qk16 = hb + 851968l;        // 1048576  [128][16][512]
  _Float16* G16T = hb + 1900544l;       // 2097152  [8][512 g][512 f]
  _Float16* M16  = hb + 3997696l;       // 2097152  [512 e][8*512 (h,g)]
  float* fb   = (float*)(hb + 6094848l);
  float* vacc = fb;                     // 16*65536 = 1048576
  float* pu   = fb + 1048576l;          // 524288   [128][8][512]
  float* pl   = fb + 1572864l;          // 1024     [128][8]  (zeroed with pu)
  float* qb   = fb + 1573888l;          // 1024
  float* gb   = fb + 1574912l;          // 4096     [8][512]
  float* qbc  = fb + 1579008l;          // 16
  float* cvec = fb + 1579024l;          // 4096     [8][512]
  float* obo8 = fb + 1583120l;          // 4096     [8][512]

  // prep (G/gb/cvec/qbc + zero pu/pl/qk16-pad) || fc1 GEMM  (short critical-path version)
  k_prepfc1<<<704, 256, 0, stream>>>(Wq, Wk, bq, bk, G16T, gb, qbc, cvec,
                                     pu, qk16, v, W1, b1, x16);
  // fc2 split-K(16): A=x16 fp16 [128x6144], B=W2 fp32 -> partials vacc[16][65536]
  k_gemm<0,1><<<dim3(16, 16, 1), 256, 0, stream>>>(x16, 6144, 0, W2, 6144, 0,
      nullptr, nullptr, nullptr, 1.f, 0, 2, vacc, nullptr, 512, 0, 2, 6, 65536);
  // vfeat -> out0/vf16  ||  M16/obo8 prep (needed only by the last GEMM)
  k_vfeat<<<768, 256, 0, stream>>>(vacc, b2, out, vf16, Wv, Wo, bv, M16, obo8);
  // qk16 = vf16 @ G16T (+cvec) batched over heads  ||  qb = vf16.gb + qbc  ||  zero out[65536..]
  k_qkqb<<<256, 256, 0, stream>>>(vf16, G16T, cvec, gb, qbc, qk16, qb, out + 65536);
  k_attn<<<NB * 4, 256, 0, stream>>>(t, tlen, qk16, qb, pu, pl);
  // attn_out = (pu/pl) @ M16 + bo + obo8[sp], split-K over heads, atomic epilogue -> output 1
  k_gemm<2,0><<<dim3(16, 8, 1), 256, 0, stream>>>(pu, 4096, 0, M16, 4096, 0,
      bo, obo8, pl, 1.f, 0, 3, out + 65536, nullptr, 512, 0, 2, 8, 0);
}